// Round 17
// baseline (663.533 us; speedup 1.0000x reference)
//
#include <hip/hip_runtime.h>
#include <math.h>

#define BGRAPH 16
#define NPG    4096
#define NPTS   (BGRAPH*NPG)   // 65536
#define KNN    20
#define NC     40
#define EPSBN  1e-5f
#define SEG    8
#define SEGN   512            // candidates per segment
#define CPTS   4              // points per conv1 block (80 edges = 5 M-tiles)
#define BIGF   3.0e38f

typedef _Float16 half8 __attribute__((ext_vector_type(8)));
typedef _Float16 h4 __attribute__((ext_vector_type(4)));
typedef unsigned short ushort8 __attribute__((ext_vector_type(8)));
typedef float f32x4 __attribute__((ext_vector_type(4)));
typedef unsigned long long u64;

// ---------------- ws layout (bytes) ----------------
#define O_X0   0u               // float[NPTS*4]      1 MB
#define O_IDX  1048576u         // int[NPTS*20]       5 MB
#define O_X1   6291456u         // fp16 x1h (8 MB) + fp16 uvh (32 MB); pkHi|pkLo overlay 80 MB (dead until conv1)
#define O_WT   90177536u        // folded weights + out2enc + Wlh + s2g/s3g + W2t/W3t

// ---------------- helpers ----------------
__device__ __forceinline__ unsigned encf(float v) {
    unsigned u = __float_as_uint(v);
    return (u & 0x80000000u) ? ~u : (u | 0x80000000u);
}
__device__ __forceinline__ float decf(unsigned k) {
    unsigned u = (k & 0x80000000u) ? (k ^ 0x80000000u) : ~k;
    return __uint_as_float(u);
}
__device__ __forceinline__ unsigned ordf(float f) {
    unsigned u = __float_as_uint(f);
    return u ^ (((unsigned)((int)u >> 31)) | 0x80000000u);
}
// monotone-equivalent distance for a fixed query row: e = sqj/2 - <xi,xj>
__device__ __forceinline__ float distE(float4 xi, float4 xj, float sqh) {
    float e = sqh;
    e = fmaf(-xi.x, xj.x, e);
    e = fmaf(-xi.y, xj.y, e);
    e = fmaf(-xi.z, xj.z, e);
    e = fmaf(-xi.w, xj.w, e);
    return e;
}
__device__ __forceinline__ unsigned uminu(unsigned a, unsigned b) { return a < b ? a : b; }
__device__ __forceinline__ unsigned umed3(unsigned a, unsigned b, unsigned c) {
    unsigned d;
    asm("v_med3_u32 %0, %1, %2, %3" : "=v"(d) : "v"(a), "v"(b), "v"(c));
    return d;
}
__device__ __forceinline__ float fmed3(float a, float b, float c) {
    float d;
    asm("v_med3_f32 %0, %1, %2, %3" : "=v"(d) : "v"(a), "v"(b), "v"(c));
    return d;
}
__device__ __forceinline__ half8 hmax8(half8 a, half8 b) {
#if __has_builtin(__builtin_elementwise_max)
    return __builtin_elementwise_max(a, b);
#else
    half8 r;
    #pragma unroll
    for (int i = 0; i < 8; ++i) r[i] = a[i] > b[i] ? a[i] : b[i];
    return r;
#endif
}

// u32 20-slot chain (merge): w0 = 20th smallest (tau) .. w19 best.
#define TK_DECL unsigned w0=0xFFFFFFFFu,w1=0xFFFFFFFFu,w2=0xFFFFFFFFu,w3=0xFFFFFFFFu,w4=0xFFFFFFFFu, \
    w5=0xFFFFFFFFu,w6=0xFFFFFFFFu,w7=0xFFFFFFFFu,w8=0xFFFFFFFFu,w9=0xFFFFFFFFu, \
    w10=0xFFFFFFFFu,w11=0xFFFFFFFFu,w12=0xFFFFFFFFu,w13=0xFFFFFFFFu,w14=0xFFFFFFFFu, \
    w15=0xFFFFFFFFu,w16=0xFFFFFFFFu,w17=0xFFFFFFFFu,w18=0xFFFFFFFFu,w19=0xFFFFFFFFu;
#define TK_INSERT(uv_) { unsigned cu = (uv_); \
    w0  = umed3(w1,  w0,  cu); \
    w1  = umed3(w2,  w1,  cu); \
    w2  = umed3(w3,  w2,  cu); \
    w3  = umed3(w4,  w3,  cu); \
    w4  = umed3(w5,  w4,  cu); \
    w5  = umed3(w6,  w5,  cu); \
    w6  = umed3(w7,  w6,  cu); \
    w7  = umed3(w8,  w7,  cu); \
    w8  = umed3(w9,  w8,  cu); \
    w9  = umed3(w10, w9,  cu); \
    w10 = umed3(w11, w10, cu); \
    w11 = umed3(w12, w11, cu); \
    w12 = umed3(w13, w12, cu); \
    w13 = umed3(w14, w13, cu); \
    w14 = umed3(w15, w14, cu); \
    w15 = umed3(w16, w15, cu); \
    w16 = umed3(w17, w16, cu); \
    w17 = umed3(w18, w17, cu); \
    w18 = umed3(w19, w18, cu); \
    w19 = uminu(w19, cu); }

// f32 20-slot chain (knn_part): f0 = tau .. f19 best. All values finite.
#define TKF_DECL float f0=BIGF,f1=BIGF,f2=BIGF,f3=BIGF,f4=BIGF,f5=BIGF,f6=BIGF,f7=BIGF,f8=BIGF,f9=BIGF, \
    f10=BIGF,f11=BIGF,f12=BIGF,f13=BIGF,f14=BIGF,f15=BIGF,f16=BIGF,f17=BIGF,f18=BIGF,f19=BIGF;
#define TKF_INSERT(dv_) { float cf = (dv_); \
    f0  = fmed3(f1,  f0,  cf); \
    f1  = fmed3(f2,  f1,  cf); \
    f2  = fmed3(f3,  f2,  cf); \
    f3  = fmed3(f4,  f3,  cf); \
    f4  = fmed3(f5,  f4,  cf); \
    f5  = fmed3(f6,  f5,  cf); \
    f6  = fmed3(f7,  f6,  cf); \
    f7  = fmed3(f8,  f7,  cf); \
    f8  = fmed3(f9,  f8,  cf); \
    f9  = fmed3(f10, f9,  cf); \
    f10 = fmed3(f11, f10, cf); \
    f11 = fmed3(f12, f11, cf); \
    f12 = fmed3(f13, f12, cf); \
    f13 = fmed3(f14, f13, cf); \
    f14 = fmed3(f15, f14, cf); \
    f15 = fmed3(f16, f15, cf); \
    f16 = fmed3(f17, f16, cf); \
    f17 = fmed3(f18, f17, cf); \
    f18 = fmed3(f19, f18, cf); \
    f19 = fminf(f19, cf); }

// ---------------- K_prep: fused x0-build + Wl transpose + BN fold + W2t/W3t/Wuvh ---------
__global__ __launch_bounds__(256) void k_prep(
        const float* __restrict__ pos, const float* __restrict__ feat,
        const float* __restrict__ Wl,
        const float* __restrict__ W1, const float* __restrict__ b1,
        const float* __restrict__ g1, const float* __restrict__ be1,
        const float* __restrict__ m1, const float* __restrict__ v1,
        const float* __restrict__ W2, const float* __restrict__ b2,
        const float* __restrict__ g2, const float* __restrict__ be2,
        const float* __restrict__ m2, const float* __restrict__ v2,
        const float* __restrict__ W3, const float* __restrict__ Wc,
        float* __restrict__ x0, _Float16* __restrict__ Wlh,
        float* __restrict__ W1f, float* __restrict__ b1f,
        float* __restrict__ b2f,
        _Float16* __restrict__ W2t, _Float16* __restrict__ W3t,
        _Float16* __restrict__ Wuvh, unsigned* __restrict__ out2enc)
{
    __shared__ float tile[32][33];
    int bx = blockIdx.x, t = threadIdx.x;
    if (bx < 256) {                       // x0 = [pos | feat]
        int i = bx*256 + t;
        float4 v;
        v.x = pos[i*3+0]; v.y = pos[i*3+1]; v.z = pos[i*3+2]; v.w = feat[i];
        ((float4*)x0)[i] = v;
    } else if (bx < 256 + 192) {          // Wlh[j][k] = fp16(Wl[k][j])
        int w = bx - 256;
        int jb = (w & 31) * 32, kb = (w >> 5) * 32;
        int tx = t & 31, ty = t >> 5;
        #pragma unroll
        for (int r = 0; r < 32; r += 8)
            tile[ty + r][tx] = Wl[(size_t)(kb + ty + r)*1024 + jb + tx];
        __syncthreads();
        #pragma unroll
        for (int r = 0; r < 32; r += 8)
            Wlh[(size_t)(jb + ty + r)*192 + kb + tx] = (_Float16)tile[tx][ty + r];
    } else if (bx == 448) {               // BN fold + Wuvh + pool-accumulator zero
        for (int i = t; i < 64; i += 256) {
            float s1 = g1[i] * rsqrtf(v1[i] + EPSBN);
            b1f[i] = (b1[i] - m1[i]) * s1 + be1[i];
            float s2 = g2[i] * rsqrtf(v2[i] + EPSBN);
            b2f[i] = (b2[i] - m2[i]) * s2 + be2[i];
        }
        for (int i = t; i < 8*64; i += 256) {
            int c = i & 63;
            W1f[i] = W1[i] * (g1[c] * rsqrtf(v1[c] + EPSBN));
        }
        for (int i = t; i < 256*64; i += 256) {
            int c = i >> 6, d = i & 63;
            float v = (c < 128) ? (Wc[d*128 + c] - Wc[(64+d)*128 + c])
                                : Wc[(64+d)*128 + (c - 128)];
            Wuvh[i] = (_Float16)v;
        }
        for (int i = t; i < 16*1024; i += 256) out2enc[i] = 0u;
    } else {                              // bx == 449: W2t/W3t = fp16 transposed (+BN fold on W2)
        for (int i = t; i < 4096; i += 256) {
            int n = i & 63, k = i >> 6;
            float s2 = g2[n] * rsqrtf(v2[n] + EPSBN);
            W2t[(size_t)n*64 + k] = (_Float16)(W2[(size_t)k*64 + n] * s2);
            W3t[(size_t)n*64 + k] = (_Float16)W3[(size_t)k*64 + n];
        }
    }
}

// ---------------- K1a: segmented kNN partials (f32 med3 chain on e-metric; SoA keys) -----
__global__ __launch_bounds__(256, 2) void k_knn_part(const float* __restrict__ x0,
        unsigned* __restrict__ pkHi, unsigned* __restrict__ pkLo)
{
    __shared__ float4 pts[SEGN];
    __shared__ float  sqh[SEGN];    // 0.5*|xj|^2
    int x  = blockIdx.x;
    int b  = x >> 7;           // graph
    int rb = (x >> 3) & 15;    // row-block
    int s  = x & 7;            // segment
    int t  = threadIdx.x;
    int r  = b*NPG + rb*256 + t;
    float4 xi = ((const float4*)x0)[r];
    #pragma unroll
    for (int l = 0; l < SEGN/256; ++l) {
        float4 v = ((const float4*)x0)[b*NPG + s*SEGN + l*256 + t];
        pts[l*256 + t] = v;
        sqh[l*256 + t] = 0.5f*(v.x*v.x + v.y*v.y + v.z*v.z + v.w*v.w);
    }
    __syncthreads();

    TKF_DECL
    #pragma unroll 8
    for (int j = 0; j < SEGN; ++j) {
        float e = distE(xi, pts[j], sqh[j]);
        TKF_INSERT(e)
    }
    float tau = f0;           // 20th smallest e in this segment

    int jbase = b*NPG + s*SEGN;
    unsigned* hcol = pkHi + (size_t)s*KNN*NPTS + r;
    unsigned* lcol = pkLo + (size_t)s*KNN*NPTS + r;
    unsigned cnt = 0, ecnt = 0;
    int e0 = 0, e1 = 0;
    #pragma unroll 4
    for (int j = 0; j < SEGN; ++j) {
        float e = distE(xi, pts[j], sqh[j]);
        if (e < tau) {
            hcol[(size_t)cnt*NPTS] = ordf(e);
            lcol[(size_t)cnt*NPTS] = (unsigned)(jbase + j);
            cnt++;
        } else if (e == tau) {
            if (ecnt == 0) e0 = j; else if (ecnt == 1) e1 = j;
            ecnt++;
        }
    }
    unsigned tauU = ordf(tau);
    if (cnt < KNN && ecnt > 0) { hcol[(size_t)cnt*NPTS] = tauU; lcol[(size_t)cnt*NPTS] = (unsigned)(jbase + e0); cnt++; }
    if (cnt < KNN && ecnt > 1) { hcol[(size_t)cnt*NPTS] = tauU; lcol[(size_t)cnt*NPTS] = (unsigned)(jbase + e1); cnt++; }
    while (cnt < KNN) {
        hcol[(size_t)cnt*NPTS] = 0xFFFFFFFFu;
        lcol[(size_t)cnt*NPTS] = (unsigned)r;
        cnt++;
    }
}

// ---------------- K1b: merge 8 partial lists (SoA) -> final 20 indices -------------------
__global__ __launch_bounds__(256, 2) void k_knn_merge(const unsigned* __restrict__ pkHi,
        const unsigned* __restrict__ pkLo, int* __restrict__ idx)
{
    int r = blockIdx.x*256 + threadIdx.x;

    TK_DECL
    #pragma unroll 4
    for (int q = 0; q < SEG*KNN; ++q) {
        unsigned u = pkHi[(size_t)q*NPTS + r];
        TK_INSERT(u)
    }
    unsigned tauU = w0;

    unsigned cnt = 0, ecnt = 0;
    int e0 = 0, e1 = 0;
    int* o = idx + (size_t)r*KNN;
    #pragma unroll 4
    for (int q = 0; q < SEG*KNN; ++q) {
        unsigned u = pkHi[(size_t)q*NPTS + r];   // L2-hot from pass 1
        if (u < tauU) {
            if (cnt < KNN) o[cnt] = (int)pkLo[(size_t)q*NPTS + r];
            cnt++;
        } else if (u == tauU) {
            if (ecnt == 0) e0 = (int)pkLo[(size_t)q*NPTS + r];
            else if (ecnt == 1) e1 = (int)pkLo[(size_t)q*NPTS + r];
            ecnt++;
        }
    }
    if (cnt < KNN && ecnt > 0) { o[cnt] = e0; cnt++; }
    if (cnt < KNN && ecnt > 1) { o[cnt] = e1; cnt++; }
    while (cnt < KNN) { o[cnt] = r; cnt++; }
}

// ---------------- K2: EdgeConv1 via MFMA; output x1h fp16 ----------------
__global__ __launch_bounds__(256) void k_conv1(const float* __restrict__ x0,
        const int* __restrict__ idx,
        const float* __restrict__ W1f, const float* __restrict__ b1f,
        const _Float16* __restrict__ W2t, const float* __restrict__ b2f,
        const _Float16* __restrict__ W3t, const float* __restrict__ b3,
        _Float16* __restrict__ x1h)
{
    __shared__ _Float16 hsbuf[2*80*72];   // hs0 | hs1 ; f32 overlay for h3
    _Float16* hs0 = hsbuf;
    _Float16* hs1 = hsbuf + 80*72;
    int t = threadIdx.x;
    int w = t >> 6, l = t & 63;
    int lr = l & 15, lg = l >> 4;

    half8 w2f[2], w3f[2];
    #pragma unroll
    for (int ks = 0; ks < 2; ++ks) {
        w2f[ks] = *(const half8*)&W2t[(size_t)(w*16 + lr)*64 + ks*32 + lg*8];
        w3f[ks] = *(const half8*)&W3t[(size_t)(w*16 + lr)*64 + ks*32 + lg*8];
    }
    float b2s = b2f[w*16 + lr];
    float b3s = b3[w*16 + lr];

    // L1: wave w owns point i, lane = channel c
    {
        int c = l;
        float w1c[8];
        #pragma unroll
        for (int f = 0; f < 8; ++f) w1c[f] = W1f[f*64 + c];
        float b1c = b1f[c];
        int i = blockIdx.x*CPTS + w;
        float4 xi = ((const float4*)x0)[i];
        #pragma unroll 4
        for (int k = 0; k < KNN; ++k) {
            int j = idx[i*KNN + k];
            float4 xj = ((const float4*)x0)[j];
            float h = b1c + xi.x*w1c[0] + xi.y*w1c[1] + xi.z*w1c[2] + xi.w*w1c[3]
                          + (xj.x-xi.x)*w1c[4] + (xj.y-xi.y)*w1c[5]
                          + (xj.z-xi.z)*w1c[6] + (xj.w-xi.w)*w1c[7];
            hs0[(w*KNN + k)*72 + c] = (_Float16)fmaxf(h, 0.0f);
        }
    }
    __syncthreads();

    // L2
    #pragma unroll
    for (int mt = 0; mt < 5; ++mt) {
        f32x4 acc = {b2s, b2s, b2s, b2s};
        #pragma unroll
        for (int ks = 0; ks < 2; ++ks) {
            half8 a = *(const half8*)&hs0[(mt*16 + lr)*72 + ks*32 + lg*8];
            acc = __builtin_amdgcn_mfma_f32_16x16x32_f16(a, w2f[ks], acc, 0, 0, 0);
        }
        #pragma unroll
        for (int jj = 0; jj < 4; ++jj)
            hs1[(mt*16 + lg*4 + jj)*72 + w*16 + lr] = (_Float16)fmaxf(acc[jj], 0.0f);
    }
    __syncthreads();

    // L3 (f32 in registers)
    float h3r[5][4];
    #pragma unroll
    for (int mt = 0; mt < 5; ++mt) {
        f32x4 acc = {b3s, b3s, b3s, b3s};
        #pragma unroll
        for (int ks = 0; ks < 2; ++ks) {
            half8 a = *(const half8*)&hs1[(mt*16 + lr)*72 + ks*32 + lg*8];
            acc = __builtin_amdgcn_mfma_f32_16x16x32_f16(a, w3f[ks], acc, 0, 0, 0);
        }
        #pragma unroll
        for (int jj = 0; jj < 4; ++jj) h3r[mt][jj] = acc[jj];
    }
    __syncthreads();

    float* h3f = (float*)hsbuf;   // [80][66] f32
    #pragma unroll
    for (int mt = 0; mt < 5; ++mt) {
        #pragma unroll
        for (int jj = 0; jj < 4; ++jj)
            h3f[(mt*16 + lg*4 + jj)*66 + w*16 + lr] = h3r[mt][jj];
    }
    __syncthreads();

    {
        float m = -3.0e38f;
        #pragma unroll 4
        for (int k = 0; k < KNN; ++k)
            m = fmaxf(m, h3f[(w*KNN + k)*66 + l]);
        x1h[(size_t)(blockIdx.x*CPTS + w)*64 + l] = (_Float16)m;
    }
}

// ---------------- K3: uvh = x1h @ [Wu | Wv] via fp16 MFMA (u' gets +bc) -----------------
__global__ __launch_bounds__(256) void k_uv(const _Float16* __restrict__ x1h,
        const _Float16* __restrict__ Wuvh, const float* __restrict__ bc,
        _Float16* __restrict__ uvh)
{
    __shared__ _Float16 Ash[64][72];
    __shared__ _Float16 Bsh[256][72];
    int m0 = blockIdx.x * 64;
    int t  = threadIdx.x;
    {
        int row = t >> 2, q = t & 3;
        const ushort8* xp = (const ushort8*)(x1h + (size_t)(m0+row)*64 + q*16);
        *(ushort8*)&Ash[row][q*16]     = xp[0];
        *(ushort8*)&Ash[row][q*16 + 8] = xp[1];
    }
    {
        const ushort8* wp = (const ushort8*)(Wuvh + (size_t)t*64);
        #pragma unroll
        for (int ch = 0; ch < 8; ++ch)
            *(ushort8*)&Bsh[t][ch*8] = wp[ch];
    }
    __syncthreads();

    int w = t >> 6, l = t & 63;
    int lr = l & 15, lg = l >> 4;
    float bch[4];
    #pragma unroll
    for (int nt = 0; nt < 4; ++nt) {
        int col = w*64 + nt*16 + lr;
        bch[nt] = (col < 128) ? bc[col] : 0.0f;
    }
    #pragma unroll
    for (int mt = 0; mt < 4; ++mt) {
        #pragma unroll
        for (int nt = 0; nt < 4; ++nt) {
            f32x4 acc = {0.f, 0.f, 0.f, 0.f};
            #pragma unroll
            for (int ks = 0; ks < 2; ++ks) {
                half8 a = *(const half8*)&Ash[mt*16 + lr][ks*32 + lg*8];
                half8 b = *(const half8*)&Bsh[w*64 + nt*16 + lr][ks*32 + lg*8];
                acc = __builtin_amdgcn_mfma_f32_16x16x32_f16(a, b, acc, 0, 0, 0);
            }
            #pragma unroll
            for (int jj = 0; jj < 4; ++jj) {
                int row = m0 + mt*16 + lg*4 + jj;
                int col = w*64 + nt*16 + lr;
                uvh[(size_t)row*256 + col] = (_Float16)(acc[jj] + bch[nt]);
            }
        }
    }
}

// ---------------- K5: out1 = [x1h | u'+max_k v] @ Wl (+bl), fused x2 + max-pool ----------
__global__ __launch_bounds__(256) void k_out1(const _Float16* __restrict__ x1h,
        const _Float16* __restrict__ uvh, const int* __restrict__ idx,
        const _Float16* __restrict__ Wlh, const float* __restrict__ bl,
        unsigned* __restrict__ out2enc)
{
    __shared__ _Float16 Asd[64][208];
    __shared__ _Float16 Bsd[128][208];
    __shared__ float red[512];
    int m0 = blockIdx.x * 64;
    int t  = threadIdx.x;
    int g  = m0 >> 12;

    {
        int row = t >> 2, q = t & 3;
        const ushort8* xp = (const ushort8*)(x1h + (size_t)(m0+row)*64 + q*16);
        *(ushort8*)&Asd[row][q*16]     = xp[0];
        *(ushort8*)&Asd[row][q*16 + 8] = xp[1];
    }
    {
        int row = t >> 2, q = t & 3;
        const int* ip = idx + (size_t)(m0 + row)*KNN;
        const _Float16* vb = uvh + 128 + q*32;
        int j0 = ip[0];
        half8 vm0 = *(const half8*)(vb + (size_t)j0*256);
        half8 vm1 = *(const half8*)(vb + (size_t)j0*256 + 8);
        half8 vm2 = *(const half8*)(vb + (size_t)j0*256 + 16);
        half8 vm3 = *(const half8*)(vb + (size_t)j0*256 + 24);
        #pragma unroll 4
        for (int k = 1; k < KNN; ++k) {
            int j = ip[k];
            vm0 = hmax8(vm0, *(const half8*)(vb + (size_t)j*256));
            vm1 = hmax8(vm1, *(const half8*)(vb + (size_t)j*256 + 8));
            vm2 = hmax8(vm2, *(const half8*)(vb + (size_t)j*256 + 16));
            vm3 = hmax8(vm3, *(const half8*)(vb + (size_t)j*256 + 24));
        }
        const _Float16* ub = uvh + (size_t)(m0+row)*256 + q*32;
        half8 u0 = *(const half8*)(ub);
        half8 u1 = *(const half8*)(ub + 8);
        half8 u2 = *(const half8*)(ub + 16);
        half8 u3 = *(const half8*)(ub + 24);
        *(half8*)&Asd[row][64 + q*32]      = u0 + vm0;
        *(half8*)&Asd[row][64 + q*32 + 8]  = u1 + vm1;
        *(half8*)&Asd[row][64 + q*32 + 16] = u2 + vm2;
        *(half8*)&Asd[row][64 + q*32 + 24] = u3 + vm3;
    }

    int w  = t >> 6, l = t & 63;
    int lr = l & 15, lg = l >> 4;
    #pragma unroll 1
    for (int np = 0; np < 8; ++np) {
        int n0 = np * 128;
        __syncthreads();
        {
            int j = t >> 1, hf = t & 1;
            const ushort8* src = (const ushort8*)(Wlh + (size_t)(n0 + j)*192 + hf*96);
            #pragma unroll
            for (int ch = 0; ch < 12; ++ch)
                *(ushort8*)&Bsd[j][hf*96 + ch*8] = src[ch];
        }
        __syncthreads();

        f32x4 acc[8];
        #pragma unroll
        for (int f = 0; f < 8; ++f) acc[f] = (f32x4){0.f, 0.f, 0.f, 0.f};
        #pragma unroll 1
        for (int ks = 0; ks < 6; ++ks) {
            half8 a = *(const half8*)&Asd[w*16 + lr][ks*32 + lg*8];
            #pragma unroll
            for (int f = 0; f < 8; ++f) {
                half8 b = *(const half8*)&Bsd[f*16 + lr][ks*32 + lg*8];
                acc[f] = __builtin_amdgcn_mfma_f32_16x16x32_f16(a, b, acc[f], 0, 0, 0);
            }
        }
        float cmax[8];
        #pragma unroll
        for (int f = 0; f < 8; ++f) {
            float m = fmaxf(fmaxf(acc[f][0], acc[f][1]), fmaxf(acc[f][2], acc[f][3]));
            m = fmaxf(m, __shfl_xor(m, 16));
            m = fmaxf(m, __shfl_xor(m, 32));
            cmax[f] = m;
        }
        if (l < 16) {
            #pragma unroll
            for (int f = 0; f < 8; ++f) red[w*128 + f*16 + l] = cmax[f];
        }
        __syncthreads();
        if (t < 128) {
            float m = fmaxf(fmaxf(red[t], red[128 + t]), fmaxf(red[256 + t], red[384 + t]));
            m += bl[n0 + t];
            atomicMax(&out2enc[g*1024 + n0 + t], encf(m));
        }
    }
}

// ---------------- K6a: head layer A, 256 blocks (g x 16 col-chunks, 8-way K-split) -------
__global__ __launch_bounds__(256) void k_headA(const unsigned* __restrict__ out2enc,
        const float* __restrict__ Wa, const float* __restrict__ ba, float* __restrict__ s2g)
{
    __shared__ float s1[1024];
    __shared__ float part[8][32];
    int g = blockIdx.x >> 4, chunk = blockIdx.x & 15;
    int t = threadIdx.x;
    for (int i = t; i < 1024; i += 256) s1[i] = decf(out2enc[g*1024 + i]);
    __syncthreads();
    int col = chunk*32 + (t & 31);
    int seg = t >> 5;
    float a0 = 0.f, a1 = 0.f, a2 = 0.f, a3 = 0.f;
    int d0 = seg*128;
    #pragma unroll 8
    for (int d = 0; d < 128; d += 4) {
        a0 = fmaf(s1[d0+d+0], Wa[(size_t)(d0+d+0)*512 + col], a0);
        a1 = fmaf(s1[d0+d+1], Wa[(size_t)(d0+d+1)*512 + col], a1);
        a2 = fmaf(s1[d0+d+2], Wa[(size_t)(d0+d+2)*512 + col], a2);
        a3 = fmaf(s1[d0+d+3], Wa[(size_t)(d0+d+3)*512 + col], a3);
    }
    part[seg][t & 31] = (a0 + a1) + (a2 + a3);
    __syncthreads();
    if (t < 32) {
        float a = 0.f;
        #pragma unroll
        for (int s = 0; s < 8; ++s) a += part[s][t];
        s2g[g*512 + chunk*32 + t] = fmaxf(ba[chunk*32 + t] + a, 0.f);
    }
}

// ---------------- K6b1: head layer B (s3 = relu(s2 @ Wb + bb)), 64 blocks ----------------
__global__ __launch_bounds__(256) void k_headB1(const float* __restrict__ s2g,
        const float* __restrict__ Wb, const float* __restrict__ bb, float* __restrict__ s3g)
{
    __shared__ float s2[512];
    __shared__ float part[4][64];
    int g = blockIdx.x >> 2, chunk = blockIdx.x & 3;
    int t = threadIdx.x;
    for (int i = t; i < 512; i += 256) s2[i] = s2g[g*512 + i];
    __syncthreads();
    int col = chunk*64 + (t & 63);
    int seg = t >> 6;                 // 0..3, each sums 128 of the 512 terms
    float a0 = 0.f, a1 = 0.f, a2 = 0.f, a3 = 0.f;
    int d0 = seg*128;
    #pragma unroll 8
    for (int d = 0; d < 128; d += 4) {
        a0 = fmaf(s2[d0+d+0], Wb[(size_t)(d0+d+0)*256 + col], a0);
        a1 = fmaf(s2[d0+d+1], Wb[(size_t)(d0+d+1)*256 + col], a1);
        a2 = fmaf(s2[d0+d+2], Wb[(size_t)(d0+d+2)*256 + col], a2);
        a3 = fmaf(s2[d0+d+3], Wb[(size_t)(d0+d+3)*256 + col], a3);
    }
    part[seg][t & 63] = (a0 + a1) + (a2 + a3);
    __syncthreads();
    if (t < 64) {
        float a = part[0][t] + part[1][t] + part[2][t] + part[3][t];
        s3g[g*256 + chunk*64 + t] = fmaxf(bb[chunk*64 + t] + a, 0.f);
    }
}

// ---------------- K6b2: logits + log_softmax, 16 blocks ----------------
__global__ __launch_bounds__(256) void k_headB2(const float* __restrict__ s3g,
        const float* __restrict__ Wo, const float* __restrict__ bo,
        float* __restrict__ out)
{
    __shared__ float s3[256];
    __shared__ float sl[NC];
    int g = blockIdx.x, t = threadIdx.x;
    s3[t] = s3g[g*256 + t];
    __syncthreads();
    if (t < NC) {
        float a = bo[t];
        #pragma unroll 8
        for (int d = 0; d < 256; ++d) a += s3[d] * Wo[d*NC + t];
        sl[t] = a;
    }
    __syncthreads();
    if (t < 64) {
        float v = (t < NC) ? sl[t] : -3.0e38f;
        float m = v;
        #pragma unroll
        for (int o2 = 32; o2 >= 1; o2 >>= 1) m = fmaxf(m, __shfl_xor(m, o2));
        float e = (t < NC) ? expf(sl[t] - m) : 0.f;
        float s = e;
        #pragma unroll
        for (int o2 = 32; o2 >= 1; o2 >>= 1) s += __shfl_xor(s, o2);
        float ls = logf(s) + m;
        if (t < NC) out[g*NC + t] = sl[t] - ls;
    }
}

// ---------------- launch ----------------
extern "C" void kernel_launch(void* const* d_in, const int* in_sizes, int n_in,
                              void* d_out, int out_size, void* d_ws, size_t ws_size,
                              hipStream_t stream)
{
    const float* pos  = (const float*)d_in[0];
    const float* feat = (const float*)d_in[1];
    const float* W1 = (const float*)d_in[2];
    const float* b1 = (const float*)d_in[3];
    const float* g1 = (const float*)d_in[4];
    const float* be1= (const float*)d_in[5];
    const float* m1 = (const float*)d_in[6];
    const float* v1 = (const float*)d_in[7];
    const float* W2 = (const float*)d_in[8];
    const float* b2 = (const float*)d_in[9];
    const float* g2 = (const float*)d_in[10];
    const float* be2= (const float*)d_in[11];
    const float* m2 = (const float*)d_in[12];
    const float* v2 = (const float*)d_in[13];
    const float* W3 = (const float*)d_in[14];
    const float* b3 = (const float*)d_in[15];
    const float* Wc = (const float*)d_in[16];
    const float* bc = (const float*)d_in[17];
    const float* Wl = (const float*)d_in[18];
    const float* bl = (const float*)d_in[19];
    const float* Wa = (const float*)d_in[20];
    const float* ba = (const float*)d_in[21];
    const float* Wb = (const float*)d_in[22];
    const float* bb = (const float*)d_in[23];
    const float* Wo = (const float*)d_in[24];
    const float* bo = (const float*)d_in[25];
    float* out = (float*)d_out;

    char* ws = (char*)d_ws;
    float* x0  = (float*)(ws + O_X0);
    int*   idx = (int*)  (ws + O_IDX);
    _Float16* x1h = (_Float16*)(ws + O_X1);                  // 8 MB
    _Float16* uvh = (_Float16*)(ws + O_X1 + 8388608u);       // 32 MB
    unsigned* pkHi = (unsigned*)(ws + O_X1);                 // 40 MB (overlay; dead after merge)
    unsigned* pkLo = pkHi + (size_t)SEG*KNN*NPTS;            // 40 MB
    float* W1f = (float*)(ws + O_WT);
    float* b1f = W1f + 512;
    float* W2f = b1f + 64;              // reserved
    float* b2f = W2f + 4096;
    _Float16* Wuvh = (_Float16*)(b2f + 64);                  // 256x64 fp16 (32 KB region)
    unsigned* out2enc = (unsigned*)((float*)(b2f + 64) + 64*256);
    _Float16* Wlh = (_Float16*)(ws + O_WT + 262144);         // 1024x192 fp16 = 384 KB
    float* s2g = (float*)(ws + O_WT + 262144 + 393216);      // 16x512 f32 = 32 KB
    _Float16* W2t = (_Float16*)(ws + O_WT + 262144 + 393216 + 32768);  // 64x64 fp16
    _Float16* W3t = W2t + 4096;                                        // 64x64 fp16
    float* s3g = (float*)(ws + O_WT + 262144 + 393216 + 49152);        // 16x256 f32 = 16 KB

    k_prep <<<450, 256, 0, stream>>>(pos, feat, Wl,
                                     W1,b1,g1,be1,m1,v1, W2,b2,g2,be2,m2,v2, W3, Wc,
                                     x0, Wlh, W1f,b1f,b2f, W2t,W3t, Wuvh,out2enc);
    k_knn_part <<<BGRAPH*16*SEG, 256, 0, stream>>>(x0, pkHi, pkLo);
    k_knn_merge<<<NPTS/256, 256, 0, stream>>>(pkHi, pkLo, idx);
    k_conv1<<<NPTS/CPTS, 256, 0, stream>>>(x0, idx, W1f, b1f, W2t, b2f, W3t, b3, x1h);
    k_uv   <<<NPTS/64, 256, 0, stream>>>(x1h, Wuvh, bc, uvh);
    k_out1 <<<1024, 256, 0, stream>>>(x1h, uvh, idx, Wlh, bl, out2enc);
    k_headA<<<BGRAPH*16, 256, 0, stream>>>(out2enc, Wa, ba, s2g);
    k_headB1<<<BGRAPH*4, 256, 0, stream>>>(s2g, Wb, bb, s3g);
    k_headB2<<<BGRAPH, 256, 0, stream>>>(s3g, Wo, bo, out);
}

// Round 18
// 540.280 us; speedup vs baseline: 1.2281x; 1.2281x over previous
//
#include <hip/hip_runtime.h>
#include <math.h>

#define BGRAPH 16
#define NPG    4096
#define NPTS   (BGRAPH*NPG)   // 65536
#define KNN    20
#define NC     40
#define EPSBN  1e-5f
#define SEG    8
#define SEGN   512            // candidates per segment
#define SEGK   12             // kept per segment (exactness via flag+fallback)
#define CPTS   4              // points per conv1 block (80 edges = 5 M-tiles)
#define BIGF   3.0e38f

typedef _Float16 half8 __attribute__((ext_vector_type(8)));
typedef _Float16 h4 __attribute__((ext_vector_type(4)));
typedef unsigned short ushort8 __attribute__((ext_vector_type(8)));
typedef float f32x4 __attribute__((ext_vector_type(4)));
typedef unsigned long long u64;

// ---------------- ws layout (bytes) ----------------
#define O_X0   0u               // float[NPTS*4]      1 MB
#define O_IDX  1048576u         // int[NPTS*20]       5 MB
#define O_X1   6291456u         // fp16 x1h (8 MB) + fp16 uvh (32 MB); pkHi|pkLo overlay 50 MB (dead until conv1)
#define O_WT   90177536u        // folded weights + out2enc + Wlh + s2g/s3g + W2t/W3t

// ---------------- helpers ----------------
__device__ __forceinline__ unsigned encf(float v) {
    unsigned u = __float_as_uint(v);
    return (u & 0x80000000u) ? ~u : (u | 0x80000000u);
}
__device__ __forceinline__ float decf(unsigned k) {
    unsigned u = (k & 0x80000000u) ? (k ^ 0x80000000u) : ~k;
    return __uint_as_float(u);
}
__device__ __forceinline__ unsigned ordf(float f) {
    unsigned u = __float_as_uint(f);
    return u ^ (((unsigned)((int)u >> 31)) | 0x80000000u);
}
// monotone-equivalent distance for a fixed query row: e = sqj/2 - <xi,xj>
__device__ __forceinline__ float distE(float4 xi, float4 xj, float sqh) {
    float e = sqh;
    e = fmaf(-xi.x, xj.x, e);
    e = fmaf(-xi.y, xj.y, e);
    e = fmaf(-xi.z, xj.z, e);
    e = fmaf(-xi.w, xj.w, e);
    return e;
}
__device__ __forceinline__ unsigned uminu(unsigned a, unsigned b) { return a < b ? a : b; }
__device__ __forceinline__ unsigned umaxu(unsigned a, unsigned b) { return a < b ? b : a; }
__device__ __forceinline__ unsigned umed3(unsigned a, unsigned b, unsigned c) {
    unsigned d;
    asm("v_med3_u32 %0, %1, %2, %3" : "=v"(d) : "v"(a), "v"(b), "v"(c));
    return d;
}
__device__ __forceinline__ float fmed3(float a, float b, float c) {
    float d;
    asm("v_med3_f32 %0, %1, %2, %3" : "=v"(d) : "v"(a), "v"(b), "v"(c));
    return d;
}
__device__ __forceinline__ half8 hmax8(half8 a, half8 b) {
#if __has_builtin(__builtin_elementwise_max)
    return __builtin_elementwise_max(a, b);
#else
    half8 r;
    #pragma unroll
    for (int i = 0; i < 8; ++i) r[i] = a[i] > b[i] ? a[i] : b[i];
    return r;
#endif
}

// u32 20-slot chain (merge): w0 = 20th smallest (tau) .. w19 best.
#define TK_DECL unsigned w0=0xFFFFFFFFu,w1=0xFFFFFFFFu,w2=0xFFFFFFFFu,w3=0xFFFFFFFFu,w4=0xFFFFFFFFu, \
    w5=0xFFFFFFFFu,w6=0xFFFFFFFFu,w7=0xFFFFFFFFu,w8=0xFFFFFFFFu,w9=0xFFFFFFFFu, \
    w10=0xFFFFFFFFu,w11=0xFFFFFFFFu,w12=0xFFFFFFFFu,w13=0xFFFFFFFFu,w14=0xFFFFFFFFu, \
    w15=0xFFFFFFFFu,w16=0xFFFFFFFFu,w17=0xFFFFFFFFu,w18=0xFFFFFFFFu,w19=0xFFFFFFFFu;
#define TK_INSERT(uv_) { unsigned cu = (uv_); \
    w0  = umed3(w1,  w0,  cu); \
    w1  = umed3(w2,  w1,  cu); \
    w2  = umed3(w3,  w2,  cu); \
    w3  = umed3(w4,  w3,  cu); \
    w4  = umed3(w5,  w4,  cu); \
    w5  = umed3(w6,  w5,  cu); \
    w6  = umed3(w7,  w6,  cu); \
    w7  = umed3(w8,  w7,  cu); \
    w8  = umed3(w9,  w8,  cu); \
    w9  = umed3(w10, w9,  cu); \
    w10 = umed3(w11, w10, cu); \
    w11 = umed3(w12, w11, cu); \
    w12 = umed3(w13, w12, cu); \
    w13 = umed3(w14, w13, cu); \
    w14 = umed3(w15, w14, cu); \
    w15 = umed3(w16, w15, cu); \
    w16 = umed3(w17, w16, cu); \
    w17 = umed3(w18, w17, cu); \
    w18 = umed3(w19, w18, cu); \
    w19 = uminu(w19, cu); }

// f32 20-slot chain (merge fallback): f0 = tau .. f19 best.
#define TKF_DECL float f0=BIGF,f1=BIGF,f2=BIGF,f3=BIGF,f4=BIGF,f5=BIGF,f6=BIGF,f7=BIGF,f8=BIGF,f9=BIGF, \
    f10=BIGF,f11=BIGF,f12=BIGF,f13=BIGF,f14=BIGF,f15=BIGF,f16=BIGF,f17=BIGF,f18=BIGF,f19=BIGF;
#define TKF_INSERT(dv_) { float cf = (dv_); \
    f0  = fmed3(f1,  f0,  cf); \
    f1  = fmed3(f2,  f1,  cf); \
    f2  = fmed3(f3,  f2,  cf); \
    f3  = fmed3(f4,  f3,  cf); \
    f4  = fmed3(f5,  f4,  cf); \
    f5  = fmed3(f6,  f5,  cf); \
    f6  = fmed3(f7,  f6,  cf); \
    f7  = fmed3(f8,  f7,  cf); \
    f8  = fmed3(f9,  f8,  cf); \
    f9  = fmed3(f10, f9,  cf); \
    f10 = fmed3(f11, f10, cf); \
    f11 = fmed3(f12, f11, cf); \
    f12 = fmed3(f13, f12, cf); \
    f13 = fmed3(f14, f13, cf); \
    f14 = fmed3(f15, f14, cf); \
    f15 = fmed3(f16, f15, cf); \
    f16 = fmed3(f17, f16, cf); \
    f17 = fmed3(f18, f17, cf); \
    f18 = fmed3(f19, f18, cf); \
    f19 = fminf(f19, cf); }

// f32 12-slot chain (knn_part): g0 = 12th smallest .. g11 best.
#define TKS_DECL float g0=BIGF,g1=BIGF,g2=BIGF,g3=BIGF,g4=BIGF,g5=BIGF, \
    g6=BIGF,g7=BIGF,g8=BIGF,g9=BIGF,g10=BIGF,g11=BIGF;
#define TKS_INSERT(dv_) { float cf = (dv_); \
    g0  = fmed3(g1,  g0,  cf); \
    g1  = fmed3(g2,  g1,  cf); \
    g2  = fmed3(g3,  g2,  cf); \
    g3  = fmed3(g4,  g3,  cf); \
    g4  = fmed3(g5,  g4,  cf); \
    g5  = fmed3(g6,  g5,  cf); \
    g6  = fmed3(g7,  g6,  cf); \
    g7  = fmed3(g8,  g7,  cf); \
    g8  = fmed3(g9,  g8,  cf); \
    g9  = fmed3(g10, g9,  cf); \
    g10 = fmed3(g11, g10, cf); \
    g11 = fminf(g11, cf); }

// ---------------- K_prep: fused x0-build + Wl transpose + BN fold + W2t/W3t/Wuvh ---------
__global__ __launch_bounds__(256) void k_prep(
        const float* __restrict__ pos, const float* __restrict__ feat,
        const float* __restrict__ Wl,
        const float* __restrict__ W1, const float* __restrict__ b1,
        const float* __restrict__ g1, const float* __restrict__ be1,
        const float* __restrict__ m1, const float* __restrict__ v1,
        const float* __restrict__ W2, const float* __restrict__ b2,
        const float* __restrict__ g2, const float* __restrict__ be2,
        const float* __restrict__ m2, const float* __restrict__ v2,
        const float* __restrict__ W3, const float* __restrict__ Wc,
        float* __restrict__ x0, _Float16* __restrict__ Wlh,
        float* __restrict__ W1f, float* __restrict__ b1f,
        float* __restrict__ b2f,
        _Float16* __restrict__ W2t, _Float16* __restrict__ W3t,
        _Float16* __restrict__ Wuvh, unsigned* __restrict__ out2enc)
{
    __shared__ float tile[32][33];
    int bx = blockIdx.x, t = threadIdx.x;
    if (bx < 256) {                       // x0 = [pos | feat]
        int i = bx*256 + t;
        float4 v;
        v.x = pos[i*3+0]; v.y = pos[i*3+1]; v.z = pos[i*3+2]; v.w = feat[i];
        ((float4*)x0)[i] = v;
    } else if (bx < 256 + 192) {          // Wlh[j][k] = fp16(Wl[k][j])
        int w = bx - 256;
        int jb = (w & 31) * 32, kb = (w >> 5) * 32;
        int tx = t & 31, ty = t >> 5;
        #pragma unroll
        for (int r = 0; r < 32; r += 8)
            tile[ty + r][tx] = Wl[(size_t)(kb + ty + r)*1024 + jb + tx];
        __syncthreads();
        #pragma unroll
        for (int r = 0; r < 32; r += 8)
            Wlh[(size_t)(jb + ty + r)*192 + kb + tx] = (_Float16)tile[tx][ty + r];
    } else if (bx == 448) {               // BN fold + Wuvh + pool-accumulator zero
        for (int i = t; i < 64; i += 256) {
            float s1 = g1[i] * rsqrtf(v1[i] + EPSBN);
            b1f[i] = (b1[i] - m1[i]) * s1 + be1[i];
            float s2 = g2[i] * rsqrtf(v2[i] + EPSBN);
            b2f[i] = (b2[i] - m2[i]) * s2 + be2[i];
        }
        for (int i = t; i < 8*64; i += 256) {
            int c = i & 63;
            W1f[i] = W1[i] * (g1[c] * rsqrtf(v1[c] + EPSBN));
        }
        for (int i = t; i < 256*64; i += 256) {
            int c = i >> 6, d = i & 63;
            float v = (c < 128) ? (Wc[d*128 + c] - Wc[(64+d)*128 + c])
                                : Wc[(64+d)*128 + (c - 128)];
            Wuvh[i] = (_Float16)v;
        }
        for (int i = t; i < 16*1024; i += 256) out2enc[i] = 0u;
    } else {                              // bx == 449: W2t/W3t = fp16 transposed (+BN fold on W2)
        for (int i = t; i < 4096; i += 256) {
            int n = i & 63, k = i >> 6;
            float s2 = g2[n] * rsqrtf(v2[n] + EPSBN);
            W2t[(size_t)n*64 + k] = (_Float16)(W2[(size_t)k*64 + n] * s2);
            W3t[(size_t)n*64 + k] = (_Float16)W3[(size_t)k*64 + n];
        }
    }
}

// ---------------- K1a: segmented kNN partials (top-12/segment, f32 med3 chain) -----------
__global__ __launch_bounds__(256, 2) void k_knn_part(const float* __restrict__ x0,
        unsigned* __restrict__ pkHi, unsigned* __restrict__ pkLo)
{
    __shared__ float4 pts[SEGN];
    __shared__ float  sqh[SEGN];    // 0.5*|xj|^2
    int x  = blockIdx.x;
    int b  = x >> 7;           // graph
    int rb = (x >> 3) & 15;    // row-block
    int s  = x & 7;            // segment
    int t  = threadIdx.x;
    int r  = b*NPG + rb*256 + t;
    float4 xi = ((const float4*)x0)[r];
    #pragma unroll
    for (int l = 0; l < SEGN/256; ++l) {
        float4 v = ((const float4*)x0)[b*NPG + s*SEGN + l*256 + t];
        pts[l*256 + t] = v;
        sqh[l*256 + t] = 0.5f*(v.x*v.x + v.y*v.y + v.z*v.z + v.w*v.w);
    }
    __syncthreads();

    TKS_DECL
    #pragma unroll 8
    for (int j = 0; j < SEGN; ++j) {
        float e = distE(xi, pts[j], sqh[j]);
        TKS_INSERT(e)
    }
    float tau = g0;           // 12th smallest e in this segment

    int jbase = b*NPG + s*SEGN;
    unsigned* hcol = pkHi + (size_t)s*SEGK*NPTS + r;
    unsigned* lcol = pkLo + (size_t)s*SEGK*NPTS + r;
    unsigned cnt = 0, ecnt = 0;
    int e0 = 0, e1 = 0;
    #pragma unroll 4
    for (int j = 0; j < SEGN; ++j) {
        float e = distE(xi, pts[j], sqh[j]);
        if (e < tau) {
            hcol[(size_t)cnt*NPTS] = ordf(e);
            lcol[(size_t)cnt*NPTS] = (unsigned)(jbase + j);
            cnt++;
        } else if (e == tau) {
            if (ecnt == 0) e0 = j; else if (ecnt == 1) e1 = j;
            ecnt++;
        }
    }
    unsigned tauU = ordf(tau);
    if (cnt < SEGK && ecnt > 0) { hcol[(size_t)cnt*NPTS] = tauU; lcol[(size_t)cnt*NPTS] = (unsigned)(jbase + e0); cnt++; }
    if (cnt < SEGK && ecnt > 1) { hcol[(size_t)cnt*NPTS] = tauU; lcol[(size_t)cnt*NPTS] = (unsigned)(jbase + e1); cnt++; }
    while (cnt < SEGK) {
        hcol[(size_t)cnt*NPTS] = 0xFFFFFFFFu;
        lcol[(size_t)cnt*NPTS] = (unsigned)r;
        cnt++;
    }
}

// ---------------- K1b: merge 8x12 partials -> final 20 (certainty flag + exact fallback) -
#define SEG_LOAD(S, SM) { unsigned km = 0u; \
    _Pragma("unroll") \
    for (int k2 = 0; k2 < SEGK; ++k2) { \
        unsigned u = pkHi[((size_t)((S)*SEGK + k2))*NPTS + r]; \
        TK_INSERT(u) \
        km = umaxu(km, u); \
    } \
    SM = km; }

__global__ __launch_bounds__(256, 2) void k_knn_merge(const float* __restrict__ x0,
        const unsigned* __restrict__ pkHi, const unsigned* __restrict__ pkLo,
        int* __restrict__ idx)
{
    int r = blockIdx.x*256 + threadIdx.x;

    TK_DECL
    unsigned sm0, sm1, sm2, sm3, sm4, sm5, sm6, sm7;
    SEG_LOAD(0, sm0) SEG_LOAD(1, sm1) SEG_LOAD(2, sm2) SEG_LOAD(3, sm3)
    SEG_LOAD(4, sm4) SEG_LOAD(5, sm5) SEG_LOAD(6, sm6) SEG_LOAD(7, sm7)
    unsigned tauU = w0;

    // flag: a segment whose 12th-kept <= prelim tau might hide a true top-20 member
    bool flag = (sm0 <= tauU) || (sm1 <= tauU) || (sm2 <= tauU) || (sm3 <= tauU) ||
                (sm4 <= tauU) || (sm5 <= tauU) || (sm6 <= tauU) || (sm7 <= tauU);

    int* o = idx + (size_t)r*KNN;
    if (!flag) {
        unsigned cnt = 0, ecnt = 0;
        int e0 = 0, e1 = 0;
        #pragma unroll 4
        for (int q = 0; q < SEG*SEGK; ++q) {
            unsigned u = pkHi[(size_t)q*NPTS + r];   // L2-hot from pass 1
            if (u < tauU) {
                if (cnt < KNN) o[cnt] = (int)pkLo[(size_t)q*NPTS + r];
                cnt++;
            } else if (u == tauU) {
                if (ecnt == 0) e0 = (int)pkLo[(size_t)q*NPTS + r];
                else if (ecnt == 1) e1 = (int)pkLo[(size_t)q*NPTS + r];
                ecnt++;
            }
        }
        if (cnt < KNN && ecnt > 0) { o[cnt] = e0; cnt++; }
        if (cnt < KNN && ecnt > 1) { o[cnt] = e1; cnt++; }
        while (cnt < KNN) { o[cnt] = r; cnt++; }
    } else {
        // exact fallback (expected ~0 rows): full-graph rescan from L2-resident x0
        int gb = r & ~(NPG - 1);
        float4 xi = ((const float4*)x0)[r];
        TKF_DECL
        #pragma unroll 1
        for (int j = 0; j < NPG; ++j) {
            float4 xj = ((const float4*)x0)[gb + j];
            float sh = 0.5f*(xj.x*xj.x + xj.y*xj.y + xj.z*xj.z + xj.w*xj.w);
            float e = distE(xi, xj, sh);
            TKF_INSERT(e)
        }
        float tauF = f0;
        unsigned cnt = 0, ecnt = 0;
        int a0 = 0, a1 = 0;
        #pragma unroll 1
        for (int j = 0; j < NPG; ++j) {
            float4 xj = ((const float4*)x0)[gb + j];
            float sh = 0.5f*(xj.x*xj.x + xj.y*xj.y + xj.z*xj.z + xj.w*xj.w);
            float e = distE(xi, xj, sh);
            if (e < tauF) {
                if (cnt < KNN) o[cnt] = gb + j;
                cnt++;
            } else if (e == tauF) {
                if (ecnt == 0) a0 = gb + j; else if (ecnt == 1) a1 = gb + j;
                ecnt++;
            }
        }
        if (cnt < KNN && ecnt > 0) { o[cnt] = a0; cnt++; }
        if (cnt < KNN && ecnt > 1) { o[cnt] = a1; cnt++; }
        while (cnt < KNN) { o[cnt] = r; cnt++; }
    }
}

// ---------------- K2: EdgeConv1 via MFMA; output x1h fp16 ----------------
__global__ __launch_bounds__(256) void k_conv1(const float* __restrict__ x0,
        const int* __restrict__ idx,
        const float* __restrict__ W1f, const float* __restrict__ b1f,
        const _Float16* __restrict__ W2t, const float* __restrict__ b2f,
        const _Float16* __restrict__ W3t, const float* __restrict__ b3,
        _Float16* __restrict__ x1h)
{
    __shared__ _Float16 hsbuf[2*80*72];   // hs0 | hs1 ; f32 overlay for h3
    _Float16* hs0 = hsbuf;
    _Float16* hs1 = hsbuf + 80*72;
    int t = threadIdx.x;
    int w = t >> 6, l = t & 63;
    int lr = l & 15, lg = l >> 4;

    half8 w2f[2], w3f[2];
    #pragma unroll
    for (int ks = 0; ks < 2; ++ks) {
        w2f[ks] = *(const half8*)&W2t[(size_t)(w*16 + lr)*64 + ks*32 + lg*8];
        w3f[ks] = *(const half8*)&W3t[(size_t)(w*16 + lr)*64 + ks*32 + lg*8];
    }
    float b2s = b2f[w*16 + lr];
    float b3s = b3[w*16 + lr];

    // L1: wave w owns point i, lane = channel c
    {
        int c = l;
        float w1c[8];
        #pragma unroll
        for (int f = 0; f < 8; ++f) w1c[f] = W1f[f*64 + c];
        float b1c = b1f[c];
        int i = blockIdx.x*CPTS + w;
        float4 xi = ((const float4*)x0)[i];
        #pragma unroll 4
        for (int k = 0; k < KNN; ++k) {
            int j = idx[i*KNN + k];
            float4 xj = ((const float4*)x0)[j];
            float h = b1c + xi.x*w1c[0] + xi.y*w1c[1] + xi.z*w1c[2] + xi.w*w1c[3]
                          + (xj.x-xi.x)*w1c[4] + (xj.y-xi.y)*w1c[5]
                          + (xj.z-xi.z)*w1c[6] + (xj.w-xi.w)*w1c[7];
            hs0[(w*KNN + k)*72 + c] = (_Float16)fmaxf(h, 0.0f);
        }
    }
    __syncthreads();

    // L2
    #pragma unroll
    for (int mt = 0; mt < 5; ++mt) {
        f32x4 acc = {b2s, b2s, b2s, b2s};
        #pragma unroll
        for (int ks = 0; ks < 2; ++ks) {
            half8 a = *(const half8*)&hs0[(mt*16 + lr)*72 + ks*32 + lg*8];
            acc = __builtin_amdgcn_mfma_f32_16x16x32_f16(a, w2f[ks], acc, 0, 0, 0);
        }
        #pragma unroll
        for (int jj = 0; jj < 4; ++jj)
            hs1[(mt*16 + lg*4 + jj)*72 + w*16 + lr] = (_Float16)fmaxf(acc[jj], 0.0f);
    }
    __syncthreads();

    // L3 (f32 in registers)
    float h3r[5][4];
    #pragma unroll
    for (int mt = 0; mt < 5; ++mt) {
        f32x4 acc = {b3s, b3s, b3s, b3s};
        #pragma unroll
        for (int ks = 0; ks < 2; ++ks) {
            half8 a = *(const half8*)&hs1[(mt*16 + lr)*72 + ks*32 + lg*8];
            acc = __builtin_amdgcn_mfma_f32_16x16x32_f16(a, w3f[ks], acc, 0, 0, 0);
        }
        #pragma unroll
        for (int jj = 0; jj < 4; ++jj) h3r[mt][jj] = acc[jj];
    }
    __syncthreads();

    float* h3f = (float*)hsbuf;   // [80][66] f32
    #pragma unroll
    for (int mt = 0; mt < 5; ++mt) {
        #pragma unroll
        for (int jj = 0; jj < 4; ++jj)
            h3f[(mt*16 + lg*4 + jj)*66 + w*16 + lr] = h3r[mt][jj];
    }
    __syncthreads();

    {
        float m = -3.0e38f;
        #pragma unroll 4
        for (int k = 0; k < KNN; ++k)
            m = fmaxf(m, h3f[(w*KNN + k)*66 + l]);
        x1h[(size_t)(blockIdx.x*CPTS + w)*64 + l] = (_Float16)m;
    }
}

// ---------------- K3: uvh = x1h @ [Wu | Wv] via fp16 MFMA (u' gets +bc) -----------------
__global__ __launch_bounds__(256) void k_uv(const _Float16* __restrict__ x1h,
        const _Float16* __restrict__ Wuvh, const float* __restrict__ bc,
        _Float16* __restrict__ uvh)
{
    __shared__ _Float16 Ash[64][72];
    __shared__ _Float16 Bsh[256][72];
    int m0 = blockIdx.x * 64;
    int t  = threadIdx.x;
    {
        int row = t >> 2, q = t & 3;
        const ushort8* xp = (const ushort8*)(x1h + (size_t)(m0+row)*64 + q*16);
        *(ushort8*)&Ash[row][q*16]     = xp[0];
        *(ushort8*)&Ash[row][q*16 + 8] = xp[1];
    }
    {
        const ushort8* wp = (const ushort8*)(Wuvh + (size_t)t*64);
        #pragma unroll
        for (int ch = 0; ch < 8; ++ch)
            *(ushort8*)&Bsh[t][ch*8] = wp[ch];
    }
    __syncthreads();

    int w = t >> 6, l = t & 63;
    int lr = l & 15, lg = l >> 4;
    float bch[4];
    #pragma unroll
    for (int nt = 0; nt < 4; ++nt) {
        int col = w*64 + nt*16 + lr;
        bch[nt] = (col < 128) ? bc[col] : 0.0f;
    }
    #pragma unroll
    for (int mt = 0; mt < 4; ++mt) {
        #pragma unroll
        for (int nt = 0; nt < 4; ++nt) {
            f32x4 acc = {0.f, 0.f, 0.f, 0.f};
            #pragma unroll
            for (int ks = 0; ks < 2; ++ks) {
                half8 a = *(const half8*)&Ash[mt*16 + lr][ks*32 + lg*8];
                half8 b = *(const half8*)&Bsh[w*64 + nt*16 + lr][ks*32 + lg*8];
                acc = __builtin_amdgcn_mfma_f32_16x16x32_f16(a, b, acc, 0, 0, 0);
            }
            #pragma unroll
            for (int jj = 0; jj < 4; ++jj) {
                int row = m0 + mt*16 + lg*4 + jj;
                int col = w*64 + nt*16 + lr;
                uvh[(size_t)row*256 + col] = (_Float16)(acc[jj] + bch[nt]);
            }
        }
    }
}

// ---------------- K5: out1 = [x1h | u'+max_k v] @ Wl (+bl), fused x2 + max-pool ----------
__global__ __launch_bounds__(256) void k_out1(const _Float16* __restrict__ x1h,
        const _Float16* __restrict__ uvh, const int* __restrict__ idx,
        const _Float16* __restrict__ Wlh, const float* __restrict__ bl,
        unsigned* __restrict__ out2enc)
{
    __shared__ _Float16 Asd[64][208];
    __shared__ _Float16 Bsd[128][208];
    __shared__ float red[512];
    int m0 = blockIdx.x * 64;
    int t  = threadIdx.x;
    int g  = m0 >> 12;

    {
        int row = t >> 2, q = t & 3;
        const ushort8* xp = (const ushort8*)(x1h + (size_t)(m0+row)*64 + q*16);
        *(ushort8*)&Asd[row][q*16]     = xp[0];
        *(ushort8*)&Asd[row][q*16 + 8] = xp[1];
    }
    {
        int row = t >> 2, q = t & 3;
        const int* ip = idx + (size_t)(m0 + row)*KNN;
        const _Float16* vb = uvh + 128 + q*32;
        int j0 = ip[0];
        half8 vm0 = *(const half8*)(vb + (size_t)j0*256);
        half8 vm1 = *(const half8*)(vb + (size_t)j0*256 + 8);
        half8 vm2 = *(const half8*)(vb + (size_t)j0*256 + 16);
        half8 vm3 = *(const half8*)(vb + (size_t)j0*256 + 24);
        #pragma unroll 4
        for (int k = 1; k < KNN; ++k) {
            int j = ip[k];
            vm0 = hmax8(vm0, *(const half8*)(vb + (size_t)j*256));
            vm1 = hmax8(vm1, *(const half8*)(vb + (size_t)j*256 + 8));
            vm2 = hmax8(vm2, *(const half8*)(vb + (size_t)j*256 + 16));
            vm3 = hmax8(vm3, *(const half8*)(vb + (size_t)j*256 + 24));
        }
        const _Float16* ub = uvh + (size_t)(m0+row)*256 + q*32;
        half8 u0 = *(const half8*)(ub);
        half8 u1 = *(const half8*)(ub + 8);
        half8 u2 = *(const half8*)(ub + 16);
        half8 u3 = *(const half8*)(ub + 24);
        *(half8*)&Asd[row][64 + q*32]      = u0 + vm0;
        *(half8*)&Asd[row][64 + q*32 + 8]  = u1 + vm1;
        *(half8*)&Asd[row][64 + q*32 + 16] = u2 + vm2;
        *(half8*)&Asd[row][64 + q*32 + 24] = u3 + vm3;
    }

    int w  = t >> 6, l = t & 63;
    int lr = l & 15, lg = l >> 4;
    #pragma unroll 1
    for (int np = 0; np < 8; ++np) {
        int n0 = np * 128;
        __syncthreads();
        {
            int j = t >> 1, hf = t & 1;
            const ushort8* src = (const ushort8*)(Wlh + (size_t)(n0 + j)*192 + hf*96);
            #pragma unroll
            for (int ch = 0; ch < 12; ++ch)
                *(ushort8*)&Bsd[j][hf*96 + ch*8] = src[ch];
        }
        __syncthreads();

        f32x4 acc[8];
        #pragma unroll
        for (int f = 0; f < 8; ++f) acc[f] = (f32x4){0.f, 0.f, 0.f, 0.f};
        #pragma unroll 1
        for (int ks = 0; ks < 6; ++ks) {
            half8 a = *(const half8*)&Asd[w*16 + lr][ks*32 + lg*8];
            #pragma unroll
            for (int f = 0; f < 8; ++f) {
                half8 b = *(const half8*)&Bsd[f*16 + lr][ks*32 + lg*8];
                acc[f] = __builtin_amdgcn_mfma_f32_16x16x32_f16(a, b, acc[f], 0, 0, 0);
            }
        }
        float cmax[8];
        #pragma unroll
        for (int f = 0; f < 8; ++f) {
            float m = fmaxf(fmaxf(acc[f][0], acc[f][1]), fmaxf(acc[f][2], acc[f][3]));
            m = fmaxf(m, __shfl_xor(m, 16));
            m = fmaxf(m, __shfl_xor(m, 32));
            cmax[f] = m;
        }
        if (l < 16) {
            #pragma unroll
            for (int f = 0; f < 8; ++f) red[w*128 + f*16 + l] = cmax[f];
        }
        __syncthreads();
        if (t < 128) {
            float m = fmaxf(fmaxf(red[t], red[128 + t]), fmaxf(red[256 + t], red[384 + t]));
            m += bl[n0 + t];
            atomicMax(&out2enc[g*1024 + n0 + t], encf(m));
        }
    }
}

// ---------------- K6a: head layer A, 256 blocks (g x 16 col-chunks, 8-way K-split) -------
__global__ __launch_bounds__(256) void k_headA(const unsigned* __restrict__ out2enc,
        const float* __restrict__ Wa, const float* __restrict__ ba, float* __restrict__ s2g)
{
    __shared__ float s1[1024];
    __shared__ float part[8][32];
    int g = blockIdx.x >> 4, chunk = blockIdx.x & 15;
    int t = threadIdx.x;
    for (int i = t; i < 1024; i += 256) s1[i] = decf(out2enc[g*1024 + i]);
    __syncthreads();
    int col = chunk*32 + (t & 31);
    int seg = t >> 5;
    float a0 = 0.f, a1 = 0.f, a2 = 0.f, a3 = 0.f;
    int d0 = seg*128;
    #pragma unroll 8
    for (int d = 0; d < 128; d += 4) {
        a0 = fmaf(s1[d0+d+0], Wa[(size_t)(d0+d+0)*512 + col], a0);
        a1 = fmaf(s1[d0+d+1], Wa[(size_t)(d0+d+1)*512 + col], a1);
        a2 = fmaf(s1[d0+d+2], Wa[(size_t)(d0+d+2)*512 + col], a2);
        a3 = fmaf(s1[d0+d+3], Wa[(size_t)(d0+d+3)*512 + col], a3);
    }
    part[seg][t & 31] = (a0 + a1) + (a2 + a3);
    __syncthreads();
    if (t < 32) {
        float a = 0.f;
        #pragma unroll
        for (int s = 0; s < 8; ++s) a += part[s][t];
        s2g[g*512 + chunk*32 + t] = fmaxf(ba[chunk*32 + t] + a, 0.f);
    }
}

// ---------------- K6b1: head layer B (s3 = relu(s2 @ Wb + bb)), 64 blocks ----------------
__global__ __launch_bounds__(256) void k_headB1(const float* __restrict__ s2g,
        const float* __restrict__ Wb, const float* __restrict__ bb, float* __restrict__ s3g)
{
    __shared__ float s2[512];
    __shared__ float part[4][64];
    int g = blockIdx.x >> 2, chunk = blockIdx.x & 3;
    int t = threadIdx.x;
    for (int i = t; i < 512; i += 256) s2[i] = s2g[g*512 + i];
    __syncthreads();
    int col = chunk*64 + (t & 63);
    int seg = t >> 6;
    float a0 = 0.f, a1 = 0.f, a2 = 0.f, a3 = 0.f;
    int d0 = seg*128;
    #pragma unroll 8
    for (int d = 0; d < 128; d += 4) {
        a0 = fmaf(s2[d0+d+0], Wb[(size_t)(d0+d+0)*256 + col], a0);
        a1 = fmaf(s2[d0+d+1], Wb[(size_t)(d0+d+1)*256 + col], a1);
        a2 = fmaf(s2[d0+d+2], Wb[(size_t)(d0+d+2)*256 + col], a2);
        a3 = fmaf(s2[d0+d+3], Wb[(size_t)(d0+d+3)*256 + col], a3);
    }
    part[seg][t & 63] = (a0 + a1) + (a2 + a3);
    __syncthreads();
    if (t < 64) {
        float a = part[0][t] + part[1][t] + part[2][t] + part[3][t];
        s3g[g*256 + chunk*64 + t] = fmaxf(bb[chunk*64 + t] + a, 0.f);
    }
}

// ---------------- K6b2: logits + log_softmax, 16 blocks ----------------
__global__ __launch_bounds__(256) void k_headB2(const float* __restrict__ s3g,
        const float* __restrict__ Wo, const float* __restrict__ bo,
        float* __restrict__ out)
{
    __shared__ float s3[256];
    __shared__ float sl[NC];
    int g = blockIdx.x, t = threadIdx.x;
    s3[t] = s3g[g*256 + t];
    __syncthreads();
    if (t < NC) {
        float a = bo[t];
        #pragma unroll 8
        for (int d = 0; d < 256; ++d) a += s3[d] * Wo[d*NC + t];
        sl[t] = a;
    }
    __syncthreads();
    if (t < 64) {
        float v = (t < NC) ? sl[t] : -3.0e38f;
        float m = v;
        #pragma unroll
        for (int o2 = 32; o2 >= 1; o2 >>= 1) m = fmaxf(m, __shfl_xor(m, o2));
        float e = (t < NC) ? expf(sl[t] - m) : 0.f;
        float s = e;
        #pragma unroll
        for (int o2 = 32; o2 >= 1; o2 >>= 1) s += __shfl_xor(s, o2);
        float ls = logf(s) + m;
        if (t < NC) out[g*NC + t] = sl[t] - ls;
    }
}

// ---------------- launch ----------------
extern "C" void kernel_launch(void* const* d_in, const int* in_sizes, int n_in,
                              void* d_out, int out_size, void* d_ws, size_t ws_size,
                              hipStream_t stream)
{
    const float* pos  = (const float*)d_in[0];
    const float* feat = (const float*)d_in[1];
    const float* W1 = (const float*)d_in[2];
    const float* b1 = (const float*)d_in[3];
    const float* g1 = (const float*)d_in[4];
    const float* be1= (const float*)d_in[5];
    const float* m1 = (const float*)d_in[6];
    const float* v1 = (const float*)d_in[7];
    const float* W2 = (const float*)d_in[8];
    const float* b2 = (const float*)d_in[9];
    const float* g2 = (const float*)d_in[10];
    const float* be2= (const float*)d_in[11];
    const float* m2 = (const float*)d_in[12];
    const float* v2 = (const float*)d_in[13];
    const float* W3 = (const float*)d_in[14];
    const float* b3 = (const float*)d_in[15];
    const float* Wc = (const float*)d_in[16];
    const float* bc = (const float*)d_in[17];
    const float* Wl = (const float*)d_in[18];
    const float* bl = (const float*)d_in[19];
    const float* Wa = (const float*)d_in[20];
    const float* ba = (const float*)d_in[21];
    const float* Wb = (const float*)d_in[22];
    const float* bb = (const float*)d_in[23];
    const float* Wo = (const float*)d_in[24];
    const float* bo = (const float*)d_in[25];
    float* out = (float*)d_out;

    char* ws = (char*)d_ws;
    float* x0  = (float*)(ws + O_X0);
    int*   idx = (int*)  (ws + O_IDX);
    _Float16* x1h = (_Float16*)(ws + O_X1);                  // 8 MB
    _Float16* uvh = (_Float16*)(ws + O_X1 + 8388608u);       // 32 MB
    unsigned* pkHi = (unsigned*)(ws + O_X1);                 // 25.2 MB (overlay; dead after merge)
    unsigned* pkLo = pkHi + (size_t)SEG*SEGK*NPTS;           // 25.2 MB
    float* W1f = (float*)(ws + O_WT);
    float* b1f = W1f + 512;
    float* W2f = b1f + 64;              // reserved
    float* b2f = W2f + 4096;
    _Float16* Wuvh = (_Float16*)(b2f + 64);                  // 256x64 fp16 (32 KB region)
    unsigned* out2enc = (unsigned*)((float*)(b2f + 64) + 64*256);
    _Float16* Wlh = (_Float16*)(ws + O_WT + 262144);         // 1024x192 fp16 = 384 KB
    float* s2g = (float*)(ws + O_WT + 262144 + 393216);      // 16x512 f32 = 32 KB
    _Float16* W2t = (_Float16*)(ws + O_WT + 262144 + 393216 + 32768);  // 64x64 fp16
    _Float16* W3t = W2t + 4096;                                        // 64x64 fp16
    float* s3g = (float*)(ws + O_WT + 262144 + 393216 + 49152);        // 16x256 f32 = 16 KB

    k_prep <<<450, 256, 0, stream>>>(pos, feat, Wl,
                                     W1,b1,g1,be1,m1,v1, W2,b2,g2,be2,m2,v2, W3, Wc,
                                     x0, Wlh, W1f,b1f,b2f, W2t,W3t, Wuvh,out2enc);
    k_knn_part <<<BGRAPH*16*SEG, 256, 0, stream>>>(x0, pkHi, pkLo);
    k_knn_merge<<<NPTS/256, 256, 0, stream>>>(x0, pkHi, pkLo, idx);
    k_conv1<<<NPTS/CPTS, 256, 0, stream>>>(x0, idx, W1f, b1f, W2t, b2f, W3t, b3, x1h);
    k_uv   <<<NPTS/64, 256, 0, stream>>>(x1h, Wuvh, bc, uvh);
    k_out1 <<<1024, 256, 0, stream>>>(x1h, uvh, idx, Wlh, bl, out2enc);
    k_headA<<<BGRAPH*16, 256, 0, stream>>>(out2enc, Wa, ba, s2g);
    k_headB1<<<BGRAPH*4, 256, 0, stream>>>(s2g, Wb, bb, s3g);
    k_headB2<<<BGRAPH, 256, 0, stream>>>(s3g, Wo, bo, out);
}